// Round 8
// baseline (1072.230 us; speedup 1.0000x reference)
//
#include <hip/hip_runtime.h>
#include <hip/hip_bf16.h>
#include <math.h>

// ---------------- problem constants ----------------
constexpr int B_ = 2, T_ = 1024, D_ = 768, H_ = 12, L_ = 4, V_ = 32000;
constexpr int M_ = B_ * T_;          // 2048 token rows
constexpr int FF_ = 4 * D_;          // 3072
constexpr int QKVN_ = 3 * D_;        // 2304
#define EMB_SCALE 27.712812921102035f
#define EPS_ 1e-5f

typedef __attribute__((ext_vector_type(8))) short short8_t;
typedef __attribute__((ext_vector_type(4))) float float4_t;

__device__ __forceinline__ float bf2f(__hip_bfloat16 v) { return __bfloat162float(v); }
__device__ __forceinline__ __hip_bfloat16 f2bf(float v) { return __float2bfloat16(v); }

// async global->LDS, 16B per lane; lds dest is wave-uniform base + lane*16
__device__ __forceinline__ void gl_lds16(const __hip_bfloat16* g, __hip_bfloat16* l) {
    __builtin_amdgcn_global_load_lds(
        (const __attribute__((address_space(1))) void*)g,
        (__attribute__((address_space(3))) void*)l, 16, 0, 0);
}

// ---------------- unified weight prep: ONE dispatch ----------------
// Sections (flat blockIdx.x):
//   [0, 24000)            : wte f32->bf16 convert, 1024 elems/block
//   [24000, 24000+9216)   : q/k/v/o transpose-convert (24x24 tiles, z=l*4+which)
//   [+9216, +18432)       : w_fc  [768,3072] -> [3072,768]  (96x24 tiles, z=l)
//   [+18432, +27648)      : w_proj [3072,768] -> [768,3072] (24x96 tiles, z=l)
// All sections independent (disjoint in/out) -> merged to overlap HBM traffic
// and remove 3 inter-dispatch bubbles.
__global__ __launch_bounds__(256) void prep_kernel(
    const float* __restrict__ wte, __hip_bfloat16* __restrict__ wte_b,
    const float* __restrict__ wq, const float* __restrict__ wk,
    const float* __restrict__ wv, const float* __restrict__ wo,
    __hip_bfloat16* __restrict__ wqkv_t, __hip_bfloat16* __restrict__ wo_t,
    const float* __restrict__ w_fc, __hip_bfloat16* __restrict__ wfc_t,
    const float* __restrict__ w_pr, __hip_bfloat16* __restrict__ wpr_t)
{
    __shared__ float tile[32][33];
    const int tid = threadIdx.x;
    int f = blockIdx.x;

    if (f < 24000) {           // ---- wte convert ----
        size_t i = ((size_t)f * 1024) + (size_t)tid * 4;
        float4 v = *(const float4*)(wte + i);
        wte_b[i + 0] = f2bf(v.x);
        wte_b[i + 1] = f2bf(v.y);
        wte_b[i + 2] = f2bf(v.z);
        wte_b[i + 3] = f2bf(v.w);
        return;
    }
    f -= 24000;

    const float* S;
    __hip_bfloat16* Dd;
    int N, K, bx, by;
    if (f < 9216) {            // ---- qkvo tconv: src [D,D] -> dst [D,D] ----
        const int z = f / 576, rem = f % 576;      // 24*24 = 576 tiles per z
        const int l = z >> 2, which = z & 3;
        const size_t dd = (size_t)D_ * D_;
        S = (which == 0 ? wq : which == 1 ? wk : which == 2 ? wv : wo) + (size_t)l * dd;
        Dd = (which < 3) ? wqkv_t + (size_t)l * QKVN_ * D_ + (size_t)which * dd
                         : wo_t + (size_t)l * dd;
        N = D_; K = D_; bx = rem % 24; by = rem / 24;
    } else if (f < 18432) {    // ---- fc tconv: src [768,3072] -> dst [3072,768] ----
        f -= 9216;
        const int z = f / 2304, rem = f % 2304;    // 96*24 = 2304 tiles per z
        S = w_fc + (size_t)z * D_ * FF_;
        Dd = wfc_t + (size_t)z * FF_ * D_;
        N = FF_; K = D_; bx = rem % 96; by = rem / 96;
    } else {                   // ---- proj tconv: src [3072,768] -> dst [768,3072] ----
        f -= 18432;
        const int z = f / 2304, rem = f % 2304;    // 24*96 = 2304 tiles per z
        S = w_pr + (size_t)z * FF_ * D_;
        Dd = wpr_t + (size_t)z * D_ * FF_;
        N = D_; K = FF_; bx = rem % 24; by = rem / 24;
    }

    const int n0 = bx * 32, k0 = by * 32;
    const int tx = tid & 31, ty = tid >> 5;        // 32 x 8
#pragma unroll
    for (int i = 0; i < 32; i += 8)
        tile[ty + i][tx] = S[(size_t)(k0 + ty + i) * N + n0 + tx];
    __syncthreads();
#pragma unroll
    for (int i = 0; i < 32; i += 8)
        Dd[(size_t)(n0 + ty + i) * K + k0 + tx] = f2bf(tile[tx][ty + i]);
}

// ---------------- DynamicTanh (optionally fused with embedding) ----------------
template <bool EMBED>
__global__ __launch_bounds__(256) void dyt_kernel(
    const float* __restrict__ xin, float* __restrict__ xout,
    __hip_bfloat16* __restrict__ h,
    const float* __restrict__ w, const float* __restrict__ bb,
    const float* __restrict__ alpha_p,
    const int* __restrict__ idx, const float* __restrict__ wte,
    const float* __restrict__ wpe)
{
    const int row = blockIdx.x, tid = threadIdx.x;
    float v[3];
    float s = 0.f, ss = 0.f;
    if (EMBED) {
        const int t = row & (T_ - 1);
        const int tok = idx[row];
#pragma unroll
        for (int i = 0; i < 3; ++i) {
            int c = i * 256 + tid;
            v[i] = (wte[(size_t)tok * D_ + c] + wpe[(size_t)t * D_ + c]) * EMB_SCALE;
            xout[(size_t)row * D_ + c] = v[i];
            s += v[i];
            ss += v[i] * v[i];
        }
    } else {
        const float* xr = xin + (size_t)row * D_;
#pragma unroll
        for (int i = 0; i < 3; ++i) {
            v[i] = xr[i * 256 + tid];
            s += v[i];
            ss += v[i] * v[i];
        }
    }
#pragma unroll
    for (int off = 32; off >= 1; off >>= 1) {
        s  += __shfl_xor(s,  off, 64);
        ss += __shfl_xor(ss, off, 64);
    }
    __shared__ float sh[8];
    int wave = tid >> 6;
    if ((tid & 63) == 0) { sh[wave] = s; sh[wave + 4] = ss; }
    __syncthreads();
    s  = sh[0] + sh[1] + sh[2] + sh[3];
    ss = sh[4] + sh[5] + sh[6] + sh[7];
    float mu = s * (1.f / D_);
    float var = ss * (1.f / D_) - mu * mu;
    float rstd = rsqrtf(var + EPS_);
    float alpha = *alpha_p;
#pragma unroll
    for (int i = 0; i < 3; ++i) {
        int c = i * 256 + tid;
        float xn = (v[i] - mu) * rstd;
        h[(size_t)row * D_ + c] = f2bf(w[c] * tanhf(alpha * xn) + bb[c]);
    }
}

// ---------------- flash attention: 256 thr, 4 waves, Q-tile 64 rows ----------------
// qkv rows [M, 2304]: q at +0, k at +768, v at +1536. o rows [M, 768].
// Pipelined staging (T14): tile kt+1's K/V global loads are ISSUED after the
// visibility barrier of tile kt, so the vmcnt(0) drain at the next WAR barrier
// lands after ~600+ cycles of QK/softmax/PV compute. Verified round 6.
constexpr int LSTR = 72;   // LDS row stride (elements); 144 B, 16B-aligned rows

__global__ __launch_bounds__(256) void fattn_kernel(
    const __hip_bfloat16* __restrict__ qkv, __hip_bfloat16* __restrict__ o)
{
    const int qt = gridDim.x - 1 - blockIdx.x;   // longest blocks first
    const int hh = blockIdx.y, b = blockIdx.z;
    const int q0 = qt * 64;
    const int tid = threadIdx.x;
    const int wave = tid >> 6, lane = tid & 63;
    const int quad = lane >> 4, l16 = lane & 15;
    const size_t rs = QKVN_;

    __shared__ __hip_bfloat16 Ks[64 * LSTR];      // [k][d]
    __shared__ __hip_bfloat16 Vts[64 * LSTR];     // [d][k] (transposed)
    __shared__ __hip_bfloat16 Ps[4][16 * LSTR];   // per-wave P strip [m][k]

    const __hip_bfloat16* qrow = qkv + (size_t)(b * T_ + q0 + wave * 16 + l16) * rs + hh * 64;
    short8_t qf0 = *(const short8_t*)(qrow + quad * 8);
    short8_t qf1 = *(const short8_t*)(qrow + 32 + quad * 8);

    float4_t Oacc[4];
#pragma unroll
    for (int j = 0; j < 4; ++j) Oacc[j] = (float4_t){0.f, 0.f, 0.f, 0.f};
    float mrow[4], lrow[4];
#pragma unroll
    for (int r = 0; r < 4; ++r) { mrow[r] = -1e30f; lrow[r] = 0.f; }

    const __hip_bfloat16* kbase = qkv + (size_t)b * T_ * rs + D_ + hh * 64;
    const __hip_bfloat16* vbase = qkv + (size_t)b * T_ * rs + 2 * D_ + hh * 64;

    const int sr = tid >> 2;            // K staging: row 0..63
    const int sc = (tid & 3) * 8;       // K staging: d chunk
    const int vr = lane;                // V staging: row (k)
    const int vc0 = wave * 16;          // V staging: d chunk start

    // preload tile 0 into regs
    uint4 kv0 = *(const uint4*)(kbase + (size_t)sr * rs + sc);
    uint4 kv1 = *(const uint4*)(kbase + (size_t)sr * rs + sc + 32);
    uint4 vv0 = *(const uint4*)(vbase + (size_t)vr * rs + vc0);
    uint4 vv1 = *(const uint4*)(vbase + (size_t)vr * rs + vc0 + 8);

    for (int kt = 0; kt <= qt; ++kt) {
        __syncthreads();   // WAR: prev tile's frag reads done (drains in-flight loads)
        *(uint4*)(Ks + sr * LSTR + sc)      = kv0;
        *(uint4*)(Ks + sr * LSTR + sc + 32) = kv1;
        {
            const __hip_bfloat16* vp = (const __hip_bfloat16*)&vv0;
#pragma unroll
            for (int i = 0; i < 8; ++i) Vts[(vc0 + i) * LSTR + vr] = vp[i];
            vp = (const __hip_bfloat16*)&vv1;
#pragma unroll
            for (int i = 0; i < 8; ++i) Vts[(vc0 + 8 + i) * LSTR + vr] = vp[i];
        }
        __syncthreads();

        // issue next tile's loads; waited at next iteration's WAR barrier
        if (kt < qt) {
            const int kn0 = (kt + 1) * 64;
            kv0 = *(const uint4*)(kbase + (size_t)(kn0 + sr) * rs + sc);
            kv1 = *(const uint4*)(kbase + (size_t)(kn0 + sr) * rs + sc + 32);
            vv0 = *(const uint4*)(vbase + (size_t)(kn0 + vr) * rs + vc0);
            vv1 = *(const uint4*)(vbase + (size_t)(kn0 + vr) * rs + vc0 + 8);
        }

        // ---- S strip = Q(16) x K^T(64) ----
        float4_t S[4];
#pragma unroll
        for (int jt = 0; jt < 4; ++jt) {
            short8_t kf0 = *(const short8_t*)(Ks + (jt * 16 + l16) * LSTR + quad * 8);
            short8_t kf1 = *(const short8_t*)(Ks + (jt * 16 + l16) * LSTR + 32 + quad * 8);
            float4_t s = (float4_t){0.f, 0.f, 0.f, 0.f};
            s = __builtin_amdgcn_mfma_f32_16x16x32_bf16(qf0, kf0, s, 0, 0, 0);
            s = __builtin_amdgcn_mfma_f32_16x16x32_bf16(qf1, kf1, s, 0, 0, 0);
            S[jt] = s;
        }

        // ---- scale + causal mask (diag tile only) ----
        if (kt == qt) {
#pragma unroll
            for (int jt = 0; jt < 4; ++jt)
#pragma unroll
                for (int r = 0; r < 4; ++r) {
                    int qg = wave * 16 + quad * 4 + r;
                    int kg = jt * 16 + l16;
                    S[jt][r] = (kg > qg) ? -1e30f : S[jt][r] * 0.125f;
                }
        } else {
#pragma unroll
            for (int jt = 0; jt < 4; ++jt)
#pragma unroll
                for (int r = 0; r < 4; ++r) S[jt][r] *= 0.125f;
        }

        // ---- online softmax (rows = quad*4+r, reduce across 16-lane group) ----
        float mnew[4], alphav[4];
#pragma unroll
        for (int r = 0; r < 4; ++r) {
            float mx = fmaxf(fmaxf(S[0][r], S[1][r]), fmaxf(S[2][r], S[3][r]));
            mx = fmaxf(mx, __shfl_xor(mx, 1, 64));
            mx = fmaxf(mx, __shfl_xor(mx, 2, 64));
            mx = fmaxf(mx, __shfl_xor(mx, 4, 64));
            mx = fmaxf(mx, __shfl_xor(mx, 8, 64));
            mnew[r] = fmaxf(mrow[r], mx);
            alphav[r] = __expf(mrow[r] - mnew[r]);
            mrow[r] = mnew[r];
        }
        float psum[4] = {0.f, 0.f, 0.f, 0.f};
#pragma unroll
        for (int jt = 0; jt < 4; ++jt)
#pragma unroll
            for (int r = 0; r < 4; ++r) {
                float p = __expf(S[jt][r] - mnew[r]);
                S[jt][r] = p;
                psum[r] += p;
            }
#pragma unroll
        for (int r = 0; r < 4; ++r) {
            float ps = psum[r];
            ps += __shfl_xor(ps, 1, 64);
            ps += __shfl_xor(ps, 2, 64);
            ps += __shfl_xor(ps, 4, 64);
            ps += __shfl_xor(ps, 8, 64);
            lrow[r] = lrow[r] * alphav[r] + ps;
        }

        // ---- P strip: C-layout regs -> LDS [m][k] (own wave only, no barrier) ----
        __hip_bfloat16* ps_base = Ps[wave];
#pragma unroll
        for (int jt = 0; jt < 4; ++jt)
#pragma unroll
            for (int r = 0; r < 4; ++r)
                ps_base[(quad * 4 + r) * LSTR + jt * 16 + l16] = f2bf(S[jt][r]);

        // ---- rescale O, then O += P @ V ----
#pragma unroll
        for (int j = 0; j < 4; ++j)
#pragma unroll
            for (int r = 0; r < 4; ++r) Oacc[j][r] *= alphav[r];

        short8_t pf0 = *(const short8_t*)(ps_base + l16 * LSTR + quad * 8);
        short8_t pf1 = *(const short8_t*)(ps_base + l16 * LSTR + 32 + quad * 8);
#pragma unroll
        for (int j = 0; j < 4; ++j) {
            short8_t vf0 = *(const short8_t*)(Vts + (j * 16 + l16) * LSTR + quad * 8);
            short8_t vf1 = *(const short8_t*)(Vts + (j * 16 + l16) * LSTR + 32 + quad * 8);
            Oacc[j] = __builtin_amdgcn_mfma_f32_16x16x32_bf16(pf0, vf0, Oacc[j], 0, 0, 0);
            Oacc[j] = __builtin_amdgcn_mfma_f32_16x16x32_bf16(pf1, vf1, Oacc[j], 0, 0, 0);
        }
    }

    // ---- epilogue: O /= l, write ----
    float inv_l[4];
#pragma unroll
    for (int r = 0; r < 4; ++r) inv_l[r] = 1.f / lrow[r];
    __hip_bfloat16* orow = o + (size_t)(b * T_ + q0 + wave * 16) * D_ + hh * 64;
#pragma unroll
    for (int j = 0; j < 4; ++j)
#pragma unroll
        for (int r = 0; r < 4; ++r)
            orow[(size_t)(quad * 4 + r) * D_ + j * 16 + l16] = f2bf(Oacc[j][r] * inv_l[r]);
}

// ---------------- pipelined GEMM: C[M,N] = A[M,K] @ Bt[N,K]^T, 128x128 tile ----------------
// Ring-4 LDS buffers (4 x 16KB), prefetch distance 3, ONE barrier + counted vmcnt per
// K-step. Granule XOR-swizzle (src-preswizzled, swizzled ds_read). Verified round 4.
__device__ __forceinline__ float gelu_exact(float t) {
    return 0.5f * t * (1.0f + erff(t * 0.70710678118654752f));
}

template <int EPI>
__global__ __launch_bounds__(256, 2) void gemm_btp(
    const __hip_bfloat16* __restrict__ A, const __hip_bfloat16* __restrict__ Bt,
    float* __restrict__ outF, __hip_bfloat16* __restrict__ outB,
    const float* __restrict__ bias, const float* __restrict__ res,
    int M, int N, int K)
{
    __shared__ __hip_bfloat16 lds[4 * 8192];   // 4 ring buffers x (A 8KB + B 8KB)
    const int tid = threadIdx.x;
    const int wave = tid >> 6, lane = tid & 63;
    const int quad = lane >> 4, l16 = lane & 15;
    const int m0 = blockIdx.y * 128, n0 = blockIdx.x * 128;
    const int wm = (wave >> 1) * 64, wn = (wave & 1) * 64;
    const int NT = K >> 5;   // K-tiles of 32 (all call sites >= 3)

    const int srow = tid >> 2;                          // 0..63
    const int sq   = (tid & 3) ^ ((srow >> 1) & 3);     // src granule (inverse swizzle)
    const __hip_bfloat16* gA = A  + (size_t)(m0 + srow) * K + sq * 8;
    const __hip_bfloat16* gB = Bt + (size_t)(n0 + srow) * K + sq * 8;
    char* ldsc = (char*)lds;
    const int wb = wave * 1024;   // this wave's 1KB within each 4KB stage chunk

#define STGP(tt) do {                                                      \
        const size_t ko = (size_t)(tt) * 32;                               \
        char* bb = ldsc + ((tt) & 3) * 16384 + wb;                         \
        gl_lds16(gA + ko,                  (__hip_bfloat16*)(bb));         \
        gl_lds16(gA + (size_t)64 * K + ko, (__hip_bfloat16*)(bb + 4096));  \
        gl_lds16(gB + ko,                  (__hip_bfloat16*)(bb + 8192));  \
        gl_lds16(gB + (size_t)64 * K + ko, (__hip_bfloat16*)(bb + 12288)); \
    } while (0)

    const int xe = (quad ^ ((l16 >> 1) & 3)) * 16;

    float4_t acc[4][4];
#pragma unroll
    for (int i = 0; i < 4; ++i)
#pragma unroll
        for (int j = 0; j < 4; ++j) acc[i][j] = (float4_t){0.f, 0.f, 0.f, 0.f};

    STGP(0); STGP(1); STGP(2);
    asm volatile("s_waitcnt vmcnt(8)" ::: "memory");
    __builtin_amdgcn_sched_barrier(0);
    __builtin_amdgcn_s_barrier();

    for (int t = 0; t < NT; ++t) {
        if (t + 3 < NT) STGP(t + 3);
        const char* base = ldsc + (t & 3) * 16384;
        short8_t af[4], bfv[4];
#pragma unroll
        for (int i = 0; i < 4; ++i)
            af[i]  = *(const short8_t*)(base + (wm + i * 16 + l16) * 64 + xe);
#pragma unroll
        for (int j = 0; j < 4; ++j)
            bfv[j] = *(const short8_t*)(base + 8192 + (wn + j * 16 + l16) * 64 + xe);
        asm volatile("s_waitcnt lgkmcnt(0)" ::: "memory");
        __builtin_amdgcn_sched_barrier(0);
        __builtin_amdgcn_s_setprio(1);
#pragma unroll
        for (int i = 0; i < 4; ++i)
#pragma unroll
            for (int j = 0; j < 4; ++j)
                acc[i][j] = __builtin_amdgcn_mfma_f32_16x16x32_bf16(
                    af[i], bfv[j], acc[i][j], 0, 0, 0);
        __builtin_amdgcn_s_setprio(0);
        if (t + 3 < NT) {
            asm volatile("s_waitcnt vmcnt(8)" ::: "memory");
        } else if (t + 2 < NT) {
            asm volatile("s_waitcnt vmcnt(4)" ::: "memory");
        } else if (t + 1 < NT) {
            asm volatile("s_waitcnt vmcnt(0)" ::: "memory");
        }
        __builtin_amdgcn_sched_barrier(0);
        __builtin_amdgcn_s_barrier();
    }
#undef STGP

#pragma unroll
    for (int i = 0; i < 4; ++i) {
#pragma unroll
        for (int j = 0; j < 4; ++j) {
            int colg = n0 + wn + j * 16 + l16;
#pragma unroll
            for (int rg = 0; rg < 4; ++rg) {
                int rowg = m0 + wm + i * 16 + quad * 4 + rg;
                size_t offo = (size_t)rowg * N + colg;
                float v = acc[i][j][rg];
                if (EPI == 0) {
                    outB[offo] = f2bf(v);
                } else if (EPI == 1) {
                    outF[offo] = res[offo] + v + bias[colg];
                } else if (EPI == 2) {
                    outB[offo] = f2bf(gelu_exact(v + bias[colg]));
                } else {
                    outF[offo] = v;
                }
            }
        }
    }
}

// ---------------- pipelined GEMM, 64x128 tile (small-N critical-path variant) ----------------
// Verified round 6. Same ring-4 ledger, 3 loads/tile: prologue 9, wait 6; loop 6/3/0.
template <int EPI>
__global__ __launch_bounds__(256, 2) void gemm_btp64(
    const __hip_bfloat16* __restrict__ A, const __hip_bfloat16* __restrict__ Bt,
    float* __restrict__ outF, __hip_bfloat16* __restrict__ outB,
    const float* __restrict__ bias, const float* __restrict__ res,
    int M, int N, int K)
{
    __shared__ __hip_bfloat16 lds[4 * 6144];   // 4 ring buffers x (A 4KB + B 8KB)
    const int tid = threadIdx.x;
    const int wave = tid >> 6, lane = tid & 63;
    const int quad = lane >> 4, l16 = lane & 15;
    const int m0 = blockIdx.y * 64, n0 = blockIdx.x * 128;
    const int wm = (wave >> 1) * 32, wn = (wave & 1) * 64;   // 2 waves M x 2 waves N
    const int NT = K >> 5;

    const int srow = tid >> 2;                          // 0..63
    const int sq   = (tid & 3) ^ ((srow >> 1) & 3);     // src granule (inverse swizzle)
    const __hip_bfloat16* gA = A  + (size_t)(m0 + srow) * K + sq * 8;
    const __hip_bfloat16* gB = Bt + (size_t)(n0 + srow) * K + sq * 8;
    char* ldsc = (char*)lds;
    const int wb = wave * 1024;

#define STGP64(tt) do {                                                    \
        const size_t ko = (size_t)(tt) * 32;                               \
        char* bb = ldsc + ((tt) & 3) * 12288 + wb;                         \
        gl_lds16(gA + ko,                  (__hip_bfloat16*)(bb));         \
        gl_lds16(gB + ko,                  (__hip_bfloat16*)(bb + 4096));  \
        gl_lds16(gB + (size_t)64 * K + ko, (__hip_bfloat16*)(bb + 8192));  \
    } while (0)

    const int xe = (quad ^ ((l16 >> 1) & 3)) * 16;

    float4_t acc[2][4];
#pragma unroll
    for (int i = 0; i < 2; ++i)
#pragma unroll
        for (int j = 0; j < 4; ++j) acc[i][j] = (float4_t){0.f, 0.f, 0.f, 0.f};

    STGP64(0); STGP64(1); STGP64(2);
    asm volatile("s_waitcnt vmcnt(6)" ::: "memory");
    __builtin_amdgcn_sched_barrier(0);
    __builtin_amdgcn_s_barrier();

    for (int t = 0; t < NT; ++t) {
        if (t + 3 < NT) STGP64(t + 3);
        const char* base = ldsc + (t & 3) * 12288;
        short8_t af[2], bfv[4];
#pragma unroll
        for (int i = 0; i < 2; ++i)
            af[i]  = *(const short8_t*)(base + (wm + i * 16 + l16) * 64 + xe);
#pragma unroll
        for (int j = 0; j < 4; ++j)
            bfv[j] = *(const short8_t*)(base + 4096 + (wn + j * 16 + l16) * 64 + xe);
        asm volatile("s_waitcnt lgkmcnt(0)" ::: "memory");
        __builtin_amdgcn_sched_barrier(0);
        __builtin_amdgcn_s_setprio(1);
#pragma unroll
        for (int i = 0; i < 2; ++i)
#pragma unroll
            for (int j = 0; j < 4; ++j)
                acc[i][j] = __builtin_amdgcn_mfma_f32_16x16x32_bf16(
                    af[i], bfv[j], acc[i][j], 0, 0, 0);
        __builtin_amdgcn_s_setprio(0);
        if (t + 3 < NT) {
            asm volatile("s_waitcnt vmcnt(6)" ::: "memory");
        } else if (t + 2 < NT) {
            asm volatile("s_waitcnt vmcnt(3)" ::: "memory");
        } else if (t + 1 < NT) {
            asm volatile("s_waitcnt vmcnt(0)" ::: "memory");
        }
        __builtin_amdgcn_sched_barrier(0);
        __builtin_amdgcn_s_barrier();
    }
#undef STGP64

#pragma unroll
    for (int i = 0; i < 2; ++i) {
#pragma unroll
        for (int j = 0; j < 4; ++j) {
            int colg = n0 + wn + j * 16 + l16;
#pragma unroll
            for (int rg = 0; rg < 4; ++rg) {
                int rowg = m0 + wm + i * 16 + quad * 4 + rg;
                size_t offo = (size_t)rowg * N + colg;
                float v = acc[i][j][rg];
                if (EPI == 0) {
                    outB[offo] = f2bf(v);
                } else if (EPI == 1) {
                    outF[offo] = res[offo] + v + bias[colg];
                } else if (EPI == 2) {
                    outB[offo] = f2bf(gelu_exact(v + bias[colg]));
                } else {
                    outF[offo] = v;
                }
            }
        }
    }
}

// ---------------- lm_head GEMM: 256x256 tile, 8 waves, ring-4 pipelined ----------------
// REVERTED to round-6 version (best measured: whole-run 1060.4); round-7's
// 2-blk/CU ring-2 variant was neutral-to-negative -> epilogue-overlap theory
// falsified. Only change: nontemporal epilogue stores (output is write-once,
// never re-read; keeps L2 for the B panels the XCD-chunked order relies on).
__global__ __launch_bounds__(512, 2) void gemm_lmhead(
    const __hip_bfloat16* __restrict__ A, const __hip_bfloat16* __restrict__ Bt,
    float* __restrict__ out)
{
    constexpr int K = D_;        // 768
    constexpr int N = V_;        // 32000
    constexpr int NT = K / 32;   // 24 K-tiles
    __shared__ __hip_bfloat16 lds[4 * 16384];   // 4 ring buffers x 32 KB = 128 KiB

    const int tid  = threadIdx.x;
    const int wave = tid >> 6, lane = tid & 63;
    const int quad = lane >> 4, l16 = lane & 15;

    const int flat = blockIdx.x;                 // 0..999
    const int g = (flat & 7) * 125 + (flat >> 3);
    const int m0 = (g & 7) * 256, n0 = (g >> 3) * 256;

    const int wm = (wave >> 2) * 128;            // 2 waves in M
    const int wn = (wave & 3) * 64;              // 4 waves in N

    const int srow = tid >> 2;
    const int sq   = (tid & 3) ^ ((srow >> 1) & 3);
    const __hip_bfloat16* gA = A  + (size_t)(m0 + srow) * K + sq * 8;
    const __hip_bfloat16* gB = Bt + (size_t)(n0 + srow) * K + sq * 8;
    char* ldsc = (char*)lds;
    const int wb = wave * 1024;

#define STGP(tt) do {                                                        \
        const size_t ko = (size_t)(tt) * 32;                                 \
        char* bb = ldsc + ((tt) & 3) * 32768 + wb;                           \
        gl_lds16(gA + ko,                   (__hip_bfloat16*)(bb));          \
        gl_lds16(gA + (size_t)128 * K + ko, (__hip_bfloat16*)(bb + 8192));   \
        gl_lds16(gB + ko,                   (__hip_bfloat16*)(bb + 16384));  \
        gl_lds16(gB + (size_t)128 * K + ko, (__hip_bfloat16*)(bb + 24576));  \
    } while (0)

    const int xe = (quad ^ ((l16 >> 1) & 3)) * 16;

    float4_t acc[8][4];
#pragma unroll
    for (int i = 0; i < 8; ++i)
#pragma unroll
        for (int j = 0; j < 4; ++j) acc[i][j] = (float4_t){0.f, 0.f, 0.f, 0.f};

    STGP(0); STGP(1); STGP(2);
    asm volatile("s_waitcnt vmcnt(8)" ::: "memory");
    __builtin_amdgcn_sched_barrier(0);
    __builtin_amdgcn_s_barrier();

    for (int t = 0; t < NT; ++t) {
        if (t + 3 < NT) STGP(t + 3);
        const char* base = ldsc + (t & 3) * 32768;
        short8_t af[8], bfv[4];
#pragma unroll
        for (int i = 0; i < 8; ++i)
            af[i]  = *(const short8_t*)(base + (wm + i * 16 + l16) * 64 + xe);
#pragma unroll
        for (int j = 0; j < 4; ++j)
            bfv[j] = *(const short8_t*)(base + 16384 + (wn + j * 16 + l16) * 64 + xe);
        asm volatile("s_waitcnt lgkmcnt(0)" ::: "memory");
        __builtin_amdgcn_sched_barrier(0);
        __builtin_amdgcn_s_setprio(1);
#pragma unroll
        for (int i = 0; i < 8; ++i)
#pragma unroll
            for (int j = 0; j < 4; ++j)
                acc[i][j] = __builtin_amdgcn_mfma_f32_16x16x32_bf16(
                    af[i], bfv[j], acc[i][j], 0, 0, 0);
        __builtin_amdgcn_s_setprio(0);
        if (t + 3 < NT) {
            asm volatile("s_waitcnt vmcnt(8)" ::: "memory");
        } else if (t + 2 < NT) {
            asm volatile("s_waitcnt vmcnt(4)" ::: "memory");
        } else if (t + 1 < NT) {
            asm volatile("s_waitcnt vmcnt(0)" ::: "memory");
        }
        __builtin_amdgcn_sched_barrier(0);
        __builtin_amdgcn_s_barrier();
    }
#undef STGP

    // nontemporal: output is write-once, never re-read -> don't pollute L2
    float* orow = out + (size_t)(m0 + wm + quad * 4) * N + (n0 + wn + l16);
#pragma unroll
    for (int i = 0; i < 8; ++i)
#pragma unroll
        for (int j = 0; j < 4; ++j)
#pragma unroll
            for (int rg = 0; rg < 4; ++rg)
                __builtin_nontemporal_store(acc[i][j][rg],
                                            &orow[(size_t)(i * 16 + rg) * N + j * 16]);
}

// ---------------- launch ----------------
extern "C" void kernel_launch(void* const* d_in, const int* in_sizes, int n_in,
                              void* d_out, int out_size, void* d_ws, size_t ws_size,
                              hipStream_t stream)
{
    const int*   idx   = (const int*)d_in[0];
    const float* wte   = (const float*)d_in[1];
    const float* wpe   = (const float*)d_in[2];
    const float* ln1_a = (const float*)d_in[3];
    const float* ln1_w = (const float*)d_in[4];
    const float* ln1_b = (const float*)d_in[5];
    const float* wq    = (const float*)d_in[6];
    const float* wk    = (const float*)d_in[7];
    const float* wv    = (const float*)d_in[8];
    const float* wo    = (const float*)d_in[9];
    const float* bo    = (const float*)d_in[10];
    const float* ln2_a = (const float*)d_in[11];
    const float* ln2_w = (const float*)d_in[12];
    const float* ln2_b = (const float*)d_in[13];
    const float* w_fc  = (const float*)d_in[14];
    const float* b_fc  = (const float*)d_in[15];
    const float* w_pr  = (const float*)d_in[16];
    const float* b_pr  = (const float*)d_in[17];
    const float* lnf_a = (const float*)d_in[18];
    const float* lnf_w = (const float*)d_in[19];
    const float* lnf_b = (const float*)d_in[20];
    float* out = (float*)d_out;

    char* ws = (char*)d_ws;
    size_t off = 0;
    auto alloc = [&](size_t bytes) -> char* {
        char* p = ws + off;
        off += (bytes + 255) & ~(size_t)255;
        return p;
    };
    __hip_bfloat16* wqkv_t = (__hip_bfloat16*)alloc((size_t)L_ * QKVN_ * D_ * 2);
    __hip_bfloat16* wo_t   = (__hip_bfloat16*)alloc((size_t)L_ * D_ * D_ * 2);
    __hip_bfloat16* wfc_t  = (__hip_bfloat16*)alloc((size_t)L_ * FF_ * D_ * 2);
    __hip_bfloat16* wpr_t  = (__hip_bfloat16*)alloc((size_t)L_ * D_ * FF_ * 2);
    __hip_bfloat16* wte_b  = (__hip_bfloat16*)alloc((size_t)V_ * D_ * 2);
    float*          x      = (float*)alloc((size_t)M_ * D_ * 4);
    __hip_bfloat16* h      = (__hip_bfloat16*)alloc((size_t)M_ * D_ * 2);
    __hip_bfloat16* qkv    = (__hip_bfloat16*)alloc((size_t)M_ * QKVN_ * 2);
    __hip_bfloat16* attno  = (__hip_bfloat16*)alloc((size_t)M_ * D_ * 2);
    __hip_bfloat16* mid    = (__hip_bfloat16*)alloc((size_t)M_ * FF_ * 2);
    (void)ws_size; (void)in_sizes; (void)n_in; (void)out_size;

    // ---- weight prep: ONE dispatch (wte convert + all tconv sections) ----
    prep_kernel<<<dim3(24000 + 3 * 9216), 256, 0, stream>>>(
        wte, wte_b, wq, wk, wv, wo, wqkv_t, wo_t, w_fc, wfc_t, w_pr, wpr_t);

    // ---- embedding fused with layer-0 ln1 DyT ----
    dyt_kernel<true><<<dim3(M_), 256, 0, stream>>>(
        nullptr, x, h, ln1_w, ln1_b, ln1_a, idx, wte, wpe);

    // ---- transformer layers ----
    for (int l = 0; l < L_; ++l) {
        if (l > 0)
            dyt_kernel<false><<<dim3(M_), 256, 0, stream>>>(
                x, nullptr, h, ln1_w + l * D_, ln1_b + l * D_, ln1_a + l,
                nullptr, nullptr, nullptr);
        gemm_btp<0><<<dim3(QKVN_ / 128, M_ / 128), 256, 0, stream>>>(
            h, wqkv_t + (size_t)l * QKVN_ * D_, nullptr, qkv, nullptr, nullptr, M_, QKVN_, D_);
        fattn_kernel<<<dim3(T_ / 64, H_, B_), 256, 0, stream>>>(qkv, attno);
        gemm_btp64<1><<<dim3(D_ / 128, M_ / 64), 256, 0, stream>>>(
            attno, wo_t + (size_t)l * D_ * D_, x, nullptr, bo + l * D_, x, M_, D_, D_);
        dyt_kernel<false><<<dim3(M_), 256, 0, stream>>>(
            x, nullptr, h, ln2_w + l * D_, ln2_b + l * D_, ln2_a + l,
            nullptr, nullptr, nullptr);
        gemm_btp<2><<<dim3(FF_ / 128, M_ / 128), 256, 0, stream>>>(
            h, wfc_t + (size_t)l * FF_ * D_, nullptr, mid, b_fc + l * FF_, nullptr, M_, FF_, D_);
        gemm_btp64<1><<<dim3(D_ / 128, M_ / 64), 256, 0, stream>>>(
            mid, wpr_t + (size_t)l * D_ * FF_, x, nullptr, b_pr + l * D_, x, M_, D_, FF_);
    }

    // ---- final DyT + lm_head (256x256 ring-4, round-6 config + nt stores) ----
    dyt_kernel<false><<<dim3(M_), 256, 0, stream>>>(
        x, nullptr, h, lnf_w, lnf_b, lnf_a, nullptr, nullptr, nullptr);
    gemm_lmhead<<<dim3((M_ / 256) * (V_ / 256)), 512, 0, stream>>>(h, wte_b, out);
}

// Round 11
// 1056.377 us; speedup vs baseline: 1.0150x; 1.0150x over previous
//
#include <hip/hip_runtime.h>
#include <hip/hip_bf16.h>
#include <math.h>

// ---------------- problem constants ----------------
constexpr int B_ = 2, T_ = 1024, D_ = 768, H_ = 12, L_ = 4, V_ = 32000;
constexpr int M_ = B_ * T_;          // 2048 token rows
constexpr int FF_ = 4 * D_;          // 3072
constexpr int QKVN_ = 3 * D_;        // 2304
#define EMB_SCALE 27.712812921102035f
#define EPS_ 1e-5f

typedef __attribute__((ext_vector_type(8))) short short8_t;
typedef __attribute__((ext_vector_type(4))) float float4_t;

__device__ __forceinline__ float bf2f(__hip_bfloat16 v) { return __bfloat162float(v); }
__device__ __forceinline__ __hip_bfloat16 f2bf(float v) { return __float2bfloat16(v); }

// async global->LDS, 16B per lane; lds dest is wave-uniform base + lane*16
__device__ __forceinline__ void gl_lds16(const __hip_bfloat16* g, __hip_bfloat16* l) {
    __builtin_amdgcn_global_load_lds(
        (const __attribute__((address_space(1))) void*)g,
        (__attribute__((address_space(3))) void*)l, 16, 0, 0);
}

// ---------------- unified weight prep: ONE dispatch ----------------
__global__ __launch_bounds__(256) void prep_kernel(
    const float* __restrict__ wte, __hip_bfloat16* __restrict__ wte_b,
    const float* __restrict__ wq, const float* __restrict__ wk,
    const float* __restrict__ wv, const float* __restrict__ wo,
    __hip_bfloat16* __restrict__ wqkv_t, __hip_bfloat16* __restrict__ wo_t,
    const float* __restrict__ w_fc, __hip_bfloat16* __restrict__ wfc_t,
    const float* __restrict__ w_pr, __hip_bfloat16* __restrict__ wpr_t)
{
    __shared__ float tile[32][33];
    const int tid = threadIdx.x;
    int f = blockIdx.x;

    if (f < 24000) {           // ---- wte convert ----
        size_t i = ((size_t)f * 1024) + (size_t)tid * 4;
        float4 v = *(const float4*)(wte + i);
        wte_b[i + 0] = f2bf(v.x);
        wte_b[i + 1] = f2bf(v.y);
        wte_b[i + 2] = f2bf(v.z);
        wte_b[i + 3] = f2bf(v.w);
        return;
    }
    f -= 24000;

    const float* S;
    __hip_bfloat16* Dd;
    int N, K, bx, by;
    if (f < 9216) {            // ---- qkvo tconv: src [D,D] -> dst [D,D] ----
        const int z = f / 576, rem = f % 576;      // 24*24 = 576 tiles per z
        const int l = z >> 2, which = z & 3;
        const size_t dd = (size_t)D_ * D_;
        S = (which == 0 ? wq : which == 1 ? wk : which == 2 ? wv : wo) + (size_t)l * dd;
        Dd = (which < 3) ? wqkv_t + (size_t)l * QKVN_ * D_ + (size_t)which * dd
                         : wo_t + (size_t)l * dd;
        N = D_; K = D_; bx = rem % 24; by = rem / 24;
    } else if (f < 18432) {    // ---- fc tconv: src [768,3072] -> dst [3072,768] ----
        f -= 9216;
        const int z = f / 2304, rem = f % 2304;    // 96*24 = 2304 tiles per z
        S = w_fc + (size_t)z * D_ * FF_;
        Dd = wfc_t + (size_t)z * FF_ * D_;
        N = FF_; K = D_; bx = rem % 96; by = rem / 96;
    } else {                   // ---- proj tconv: src [3072,768] -> dst [768,3072] ----
        f -= 18432;
        const int z = f / 2304, rem = f % 2304;    // 24*96 = 2304 tiles per z
        S = w_pr + (size_t)z * FF_ * D_;
        Dd = wpr_t + (size_t)z * D_ * FF_;
        N = D_; K = FF_; bx = rem % 24; by = rem / 24;
    }

    const int n0 = bx * 32, k0 = by * 32;
    const int tx = tid & 31, ty = tid >> 5;        // 32 x 8
#pragma unroll
    for (int i = 0; i < 32; i += 8)
        tile[ty + i][tx] = S[(size_t)(k0 + ty + i) * N + n0 + tx];
    __syncthreads();
#pragma unroll
    for (int i = 0; i < 32; i += 8)
        Dd[(size_t)(n0 + ty + i) * K + k0 + tx] = f2bf(tile[tx][ty + i]);
}

// ---------------- DynamicTanh (optionally fused with embedding) ----------------
template <bool EMBED>
__global__ __launch_bounds__(256) void dyt_kernel(
    const float* __restrict__ xin, float* __restrict__ xout,
    __hip_bfloat16* __restrict__ h,
    const float* __restrict__ w, const float* __restrict__ bb,
    const float* __restrict__ alpha_p,
    const int* __restrict__ idx, const float* __restrict__ wte,
    const float* __restrict__ wpe)
{
    const int row = blockIdx.x, tid = threadIdx.x;
    float v[3];
    float s = 0.f, ss = 0.f;
    if (EMBED) {
        const int t = row & (T_ - 1);
        const int tok = idx[row];
#pragma unroll
        for (int i = 0; i < 3; ++i) {
            int c = i * 256 + tid;
            v[i] = (wte[(size_t)tok * D_ + c] + wpe[(size_t)t * D_ + c]) * EMB_SCALE;
            xout[(size_t)row * D_ + c] = v[i];
            s += v[i];
            ss += v[i] * v[i];
        }
    } else {
        const float* xr = xin + (size_t)row * D_;
#pragma unroll
        for (int i = 0; i < 3; ++i) {
            v[i] = xr[i * 256 + tid];
            s += v[i];
            ss += v[i] * v[i];
        }
    }
#pragma unroll
    for (int off = 32; off >= 1; off >>= 1) {
        s  += __shfl_xor(s,  off, 64);
        ss += __shfl_xor(ss, off, 64);
    }
    __shared__ float sh[8];
    int wave = tid >> 6;
    if ((tid & 63) == 0) { sh[wave] = s; sh[wave + 4] = ss; }
    __syncthreads();
    s  = sh[0] + sh[1] + sh[2] + sh[3];
    ss = sh[4] + sh[5] + sh[6] + sh[7];
    float mu = s * (1.f / D_);
    float var = ss * (1.f / D_) - mu * mu;
    float rstd = rsqrtf(var + EPS_);
    float alpha = *alpha_p;
#pragma unroll
    for (int i = 0; i < 3; ++i) {
        int c = i * 256 + tid;
        float xn = (v[i] - mu) * rstd;
        h[(size_t)row * D_ + c] = f2bf(w[c] * tanhf(alpha * xn) + bb[c]);
    }
}

// ---------------- flash attention: 256 thr, 4 waves, Q-tile 64 rows ----------------
// Verified round 6 (register-prefetch pipelined staging).
constexpr int LSTR = 72;   // LDS row stride (elements); 144 B, 16B-aligned rows

__global__ __launch_bounds__(256) void fattn_kernel(
    const __hip_bfloat16* __restrict__ qkv, __hip_bfloat16* __restrict__ o)
{
    const int qt = gridDim.x - 1 - blockIdx.x;   // longest blocks first
    const int hh = blockIdx.y, b = blockIdx.z;
    const int q0 = qt * 64;
    const int tid = threadIdx.x;
    const int wave = tid >> 6, lane = tid & 63;
    const int quad = lane >> 4, l16 = lane & 15;
    const size_t rs = QKVN_;

    __shared__ __hip_bfloat16 Ks[64 * LSTR];      // [k][d]
    __shared__ __hip_bfloat16 Vts[64 * LSTR];     // [d][k] (transposed)
    __shared__ __hip_bfloat16 Ps[4][16 * LSTR];   // per-wave P strip [m][k]

    const __hip_bfloat16* qrow = qkv + (size_t)(b * T_ + q0 + wave * 16 + l16) * rs + hh * 64;
    short8_t qf0 = *(const short8_t*)(qrow + quad * 8);
    short8_t qf1 = *(const short8_t*)(qrow + 32 + quad * 8);

    float4_t Oacc[4];
#pragma unroll
    for (int j = 0; j < 4; ++j) Oacc[j] = (float4_t){0.f, 0.f, 0.f, 0.f};
    float mrow[4], lrow[4];
#pragma unroll
    for (int r = 0; r < 4; ++r) { mrow[r] = -1e30f; lrow[r] = 0.f; }

    const __hip_bfloat16* kbase = qkv + (size_t)b * T_ * rs + D_ + hh * 64;
    const __hip_bfloat16* vbase = qkv + (size_t)b * T_ * rs + 2 * D_ + hh * 64;

    const int sr = tid >> 2;            // K staging: row 0..63
    const int sc = (tid & 3) * 8;       // K staging: d chunk
    const int vr = lane;                // V staging: row (k)
    const int vc0 = wave * 16;          // V staging: d chunk start

    // preload tile 0 into regs
    uint4 kv0 = *(const uint4*)(kbase + (size_t)sr * rs + sc);
    uint4 kv1 = *(const uint4*)(kbase + (size_t)sr * rs + sc + 32);
    uint4 vv0 = *(const uint4*)(vbase + (size_t)vr * rs + vc0);
    uint4 vv1 = *(const uint4*)(vbase + (size_t)vr * rs + vc0 + 8);

    for (int kt = 0; kt <= qt; ++kt) {
        __syncthreads();   // WAR: prev tile's frag reads done (drains in-flight loads)
        *(uint4*)(Ks + sr * LSTR + sc)      = kv0;
        *(uint4*)(Ks + sr * LSTR + sc + 32) = kv1;
        {
            const __hip_bfloat16* vp = (const __hip_bfloat16*)&vv0;
#pragma unroll
            for (int i = 0; i < 8; ++i) Vts[(vc0 + i) * LSTR + vr] = vp[i];
            vp = (const __hip_bfloat16*)&vv1;
#pragma unroll
            for (int i = 0; i < 8; ++i) Vts[(vc0 + 8 + i) * LSTR + vr] = vp[i];
        }
        __syncthreads();

        // issue next tile's loads; waited at next iteration's WAR barrier
        if (kt < qt) {
            const int kn0 = (kt + 1) * 64;
            kv0 = *(const uint4*)(kbase + (size_t)(kn0 + sr) * rs + sc);
            kv1 = *(const uint4*)(kbase + (size_t)(kn0 + sr) * rs + sc + 32);
            vv0 = *(const uint4*)(vbase + (size_t)(kn0 + vr) * rs + vc0);
            vv1 = *(const uint4*)(vbase + (size_t)(kn0 + vr) * rs + vc0 + 8);
        }

        // ---- S strip = Q(16) x K^T(64) ----
        float4_t S[4];
#pragma unroll
        for (int jt = 0; jt < 4; ++jt) {
            short8_t kf0 = *(const short8_t*)(Ks + (jt * 16 + l16) * LSTR + quad * 8);
            short8_t kf1 = *(const short8_t*)(Ks + (jt * 16 + l16) * LSTR + 32 + quad * 8);
            float4_t s = (float4_t){0.f, 0.f, 0.f, 0.f};
            s = __builtin_amdgcn_mfma_f32_16x16x32_bf16(qf0, kf0, s, 0, 0, 0);
            s = __builtin_amdgcn_mfma_f32_16x16x32_bf16(qf1, kf1, s, 0, 0, 0);
            S[jt] = s;
        }

        // ---- scale + causal mask (diag tile only) ----
        if (kt == qt) {
#pragma unroll
            for (int jt = 0; jt < 4; ++jt)
#pragma unroll
                for (int r = 0; r < 4; ++r) {
                    int qg = wave * 16 + quad * 4 + r;
                    int kg = jt * 16 + l16;
                    S[jt][r] = (kg > qg) ? -1e30f : S[jt][r] * 0.125f;
                }
        } else {
#pragma unroll
            for (int jt = 0; jt < 4; ++jt)
#pragma unroll
                for (int r = 0; r < 4; ++r) S[jt][r] *= 0.125f;
        }

        // ---- online softmax (rows = quad*4+r, reduce across 16-lane group) ----
        float mnew[4], alphav[4];
#pragma unroll
        for (int r = 0; r < 4; ++r) {
            float mx = fmaxf(fmaxf(S[0][r], S[1][r]), fmaxf(S[2][r], S[3][r]));
            mx = fmaxf(mx, __shfl_xor(mx, 1, 64));
            mx = fmaxf(mx, __shfl_xor(mx, 2, 64));
            mx = fmaxf(mx, __shfl_xor(mx, 4, 64));
            mx = fmaxf(mx, __shfl_xor(mx, 8, 64));
            mnew[r] = fmaxf(mrow[r], mx);
            alphav[r] = __expf(mrow[r] - mnew[r]);
            mrow[r] = mnew[r];
        }
        float psum[4] = {0.f, 0.f, 0.f, 0.f};
#pragma unroll
        for (int jt = 0; jt < 4; ++jt)
#pragma unroll
            for (int r = 0; r < 4; ++r) {
                float p = __expf(S[jt][r] - mnew[r]);
                S[jt][r] = p;
                psum[r] += p;
            }
#pragma unroll
        for (int r = 0; r < 4; ++r) {
            float ps = psum[r];
            ps += __shfl_xor(ps, 1, 64);
            ps += __shfl_xor(ps, 2, 64);
            ps += __shfl_xor(ps, 4, 64);
            ps += __shfl_xor(ps, 8, 64);
            lrow[r] = lrow[r] * alphav[r] + ps;
        }

        // ---- P strip: C-layout regs -> LDS [m][k] (own wave only, no barrier) ----
        __hip_bfloat16* ps_base = Ps[wave];
#pragma unroll
        for (int jt = 0; jt < 4; ++jt)
#pragma unroll
            for (int r = 0; r < 4; ++r)
                ps_base[(quad * 4 + r) * LSTR + jt * 16 + l16] = f2bf(S[jt][r]);

        // ---- rescale O, then O += P @ V ----
#pragma unroll
        for (int j = 0; j < 4; ++j)
#pragma unroll
            for (int r = 0; r < 4; ++r) Oacc[j][r] *= alphav[r];

        short8_t pf0 = *(const short8_t*)(ps_base + l16 * LSTR + quad * 8);
        short8_t pf1 = *(const short8_t*)(ps_base + l16 * LSTR + 32 + quad * 8);
#pragma unroll
        for (int j = 0; j < 4; ++j) {
            short8_t vf0 = *(const short8_t*)(Vts + (j * 16 + l16) * LSTR + quad * 8);
            short8_t vf1 = *(const short8_t*)(Vts + (j * 16 + l16) * LSTR + 32 + quad * 8);
            Oacc[j] = __builtin_amdgcn_mfma_f32_16x16x32_bf16(pf0, vf0, Oacc[j], 0, 0, 0);
            Oacc[j] = __builtin_amdgcn_mfma_f32_16x16x32_bf16(pf1, vf1, Oacc[j], 0, 0, 0);
        }
    }

    // ---- epilogue: O /= l, write ----
    float inv_l[4];
#pragma unroll
    for (int r = 0; r < 4; ++r) inv_l[r] = 1.f / lrow[r];
    __hip_bfloat16* orow = o + (size_t)(b * T_ + q0 + wave * 16) * D_ + hh * 64;
#pragma unroll
    for (int j = 0; j < 4; ++j)
#pragma unroll
        for (int r = 0; r < 4; ++r)
            orow[(size_t)(quad * 4 + r) * D_ + j * 16 + l16] = f2bf(Oacc[j][r] * inv_l[r]);
}

// ---------------- pipelined GEMM: C[M,N] = A[M,K] @ Bt[N,K]^T, 128x128 tile ----------------
// Ring-4, distance 3, counted vmcnt, explicit lgkm drain before MFMA
// (round-8-verified schedule; the R9 lgkm-removal variant killed the container
// twice -> reverted).
__device__ __forceinline__ float gelu_exact(float t) {
    return 0.5f * t * (1.0f + erff(t * 0.70710678118654752f));
}

template <int EPI>
__global__ __launch_bounds__(256, 2) void gemm_btp(
    const __hip_bfloat16* __restrict__ A, const __hip_bfloat16* __restrict__ Bt,
    float* __restrict__ outF, __hip_bfloat16* __restrict__ outB,
    const float* __restrict__ bias, const float* __restrict__ res,
    int M, int N, int K)
{
    __shared__ __hip_bfloat16 lds[4 * 8192];   // 4 ring buffers x (A 8KB + B 8KB)
    const int tid = threadIdx.x;
    const int wave = tid >> 6, lane = tid & 63;
    const int quad = lane >> 4, l16 = lane & 15;
    const int m0 = blockIdx.y * 128, n0 = blockIdx.x * 128;
    const int wm = (wave >> 1) * 64, wn = (wave & 1) * 64;
    const int NT = K >> 5;   // K-tiles of 32 (all call sites >= 3)

    const int srow = tid >> 2;                          // 0..63
    const int sq   = (tid & 3) ^ ((srow >> 1) & 3);     // src granule (inverse swizzle)
    const __hip_bfloat16* gA = A  + (size_t)(m0 + srow) * K + sq * 8;
    const __hip_bfloat16* gB = Bt + (size_t)(n0 + srow) * K + sq * 8;
    char* ldsc = (char*)lds;
    const int wb = wave * 1024;   // this wave's 1KB within each 4KB stage chunk

#define STGP(tt) do {                                                      \
        const size_t ko = (size_t)(tt) * 32;                               \
        char* bb = ldsc + ((tt) & 3) * 16384 + wb;                         \
        gl_lds16(gA + ko,                  (__hip_bfloat16*)(bb));         \
        gl_lds16(gA + (size_t)64 * K + ko, (__hip_bfloat16*)(bb + 4096));  \
        gl_lds16(gB + ko,                  (__hip_bfloat16*)(bb + 8192));  \
        gl_lds16(gB + (size_t)64 * K + ko, (__hip_bfloat16*)(bb + 12288)); \
    } while (0)

    const int xe = (quad ^ ((l16 >> 1) & 3)) * 16;

    float4_t acc[4][4];
#pragma unroll
    for (int i = 0; i < 4; ++i)
#pragma unroll
        for (int j = 0; j < 4; ++j) acc[i][j] = (float4_t){0.f, 0.f, 0.f, 0.f};

    STGP(0); STGP(1); STGP(2);
    asm volatile("s_waitcnt vmcnt(8)" ::: "memory");
    __builtin_amdgcn_sched_barrier(0);
    __builtin_amdgcn_s_barrier();

    for (int t = 0; t < NT; ++t) {
        if (t + 3 < NT) STGP(t + 3);
        const char* base = ldsc + (t & 3) * 16384;
        short8_t af[4], bfv[4];
#pragma unroll
        for (int i = 0; i < 4; ++i)
            af[i]  = *(const short8_t*)(base + (wm + i * 16 + l16) * 64 + xe);
#pragma unroll
        for (int j = 0; j < 4; ++j)
            bfv[j] = *(const short8_t*)(base + 8192 + (wn + j * 16 + l16) * 64 + xe);
        asm volatile("s_waitcnt lgkmcnt(0)" ::: "memory");
        __builtin_amdgcn_sched_barrier(0);
        __builtin_amdgcn_s_setprio(1);
#pragma unroll
        for (int i = 0; i < 4; ++i)
#pragma unroll
            for (int j = 0; j < 4; ++j)
                acc[i][j] = __builtin_amdgcn_mfma_f32_16x16x32_bf16(
                    af[i], bfv[j], acc[i][j], 0, 0, 0);
        __builtin_amdgcn_s_setprio(0);
        if (t + 3 < NT) {
            asm volatile("s_waitcnt vmcnt(8)" ::: "memory");
        } else if (t + 2 < NT) {
            asm volatile("s_waitcnt vmcnt(4)" ::: "memory");
        } else if (t + 1 < NT) {
            asm volatile("s_waitcnt vmcnt(0)" ::: "memory");
        }
        __builtin_amdgcn_sched_barrier(0);
        __builtin_amdgcn_s_barrier();
    }
#undef STGP

#pragma unroll
    for (int i = 0; i < 4; ++i) {
#pragma unroll
        for (int j = 0; j < 4; ++j) {
            int colg = n0 + wn + j * 16 + l16;
#pragma unroll
            for (int rg = 0; rg < 4; ++rg) {
                int rowg = m0 + wm + i * 16 + quad * 4 + rg;
                size_t offo = (size_t)rowg * N + colg;
                float v = acc[i][j][rg];
                if (EPI == 0) {
                    outB[offo] = f2bf(v);
                } else if (EPI == 1) {
                    outF[offo] = res[offo] + v + bias[colg];
                } else if (EPI == 2) {
                    outB[offo] = f2bf(gelu_exact(v + bias[colg]));
                } else {
                    outF[offo] = v;
                }
            }
        }
    }
}

// ---------------- pipelined GEMM, 64x128 tile (small-N critical-path variant) ----------------
// Verified round 6. Ring-4 ledger, 3 loads/tile: prologue 9, wait 6; loop 6/3/0.
template <int EPI>
__global__ __launch_bounds__(256, 2) void gemm_btp64(
    const __hip_bfloat16* __restrict__ A, const __hip_bfloat16* __restrict__ Bt,
    float* __restrict__ outF, __hip_bfloat16* __restrict__ outB,
    const float* __restrict__ bias, const float* __restrict__ res,
    int M, int N, int K)
{
    __shared__ __hip_bfloat16 lds[4 * 6144];   // 4 ring buffers x (A 4KB + B 8KB)
    const int tid = threadIdx.x;
    const int wave = tid >> 6, lane = tid & 63;
    const int quad = lane >> 4, l16 = lane & 15;
    const int m0 = blockIdx.y * 64, n0 = blockIdx.x * 128;
    const int wm = (wave >> 1) * 32, wn = (wave & 1) * 64;   // 2 waves M x 2 waves N
    const int NT = K >> 5;

    const int srow = tid >> 2;                          // 0..63
    const int sq   = (tid & 3) ^ ((srow >> 1) & 3);     // src granule (inverse swizzle)
    const __hip_bfloat16* gA = A  + (size_t)(m0 + srow) * K + sq * 8;
    const __hip_bfloat16* gB = Bt + (size_t)(n0 + srow) * K + sq * 8;
    char* ldsc = (char*)lds;
    const int wb = wave * 1024;

#define STGP64(tt) do {                                                    \
        const size_t ko = (size_t)(tt) * 32;                               \
        char* bb = ldsc + ((tt) & 3) * 12288 + wb;                         \
        gl_lds16(gA + ko,                  (__hip_bfloat16*)(bb));         \
        gl_lds16(gB + ko,                  (__hip_bfloat16*)(bb + 4096));  \
        gl_lds16(gB + (size_t)64 * K + ko, (__hip_bfloat16*)(bb + 8192));  \
    } while (0)

    const int xe = (quad ^ ((l16 >> 1) & 3)) * 16;

    float4_t acc[2][4];
#pragma unroll
    for (int i = 0; i < 2; ++i)
#pragma unroll
        for (int j = 0; j < 4; ++j) acc[i][j] = (float4_t){0.f, 0.f, 0.f, 0.f};

    STGP64(0); STGP64(1); STGP64(2);
    asm volatile("s_waitcnt vmcnt(6)" ::: "memory");
    __builtin_amdgcn_sched_barrier(0);
    __builtin_amdgcn_s_barrier();

    for (int t = 0; t < NT; ++t) {
        if (t + 3 < NT) STGP64(t + 3);
        const char* base = ldsc + (t & 3) * 12288;
        short8_t af[2], bfv[4];
#pragma unroll
        for (int i = 0; i < 2; ++i)
            af[i]  = *(const short8_t*)(base + (wm + i * 16 + l16) * 64 + xe);
#pragma unroll
        for (int j = 0; j < 4; ++j)
            bfv[j] = *(const short8_t*)(base + 4096 + (wn + j * 16 + l16) * 64 + xe);
        asm volatile("s_waitcnt lgkmcnt(0)" ::: "memory");
        __builtin_amdgcn_sched_barrier(0);
        __builtin_amdgcn_s_setprio(1);
#pragma unroll
        for (int i = 0; i < 2; ++i)
#pragma unroll
            for (int j = 0; j < 4; ++j)
                acc[i][j] = __builtin_amdgcn_mfma_f32_16x16x32_bf16(
                    af[i], bfv[j], acc[i][j], 0, 0, 0);
        __builtin_amdgcn_s_setprio(0);
        if (t + 3 < NT) {
            asm volatile("s_waitcnt vmcnt(6)" ::: "memory");
        } else if (t + 2 < NT) {
            asm volatile("s_waitcnt vmcnt(3)" ::: "memory");
        } else if (t + 1 < NT) {
            asm volatile("s_waitcnt vmcnt(0)" ::: "memory");
        }
        __builtin_amdgcn_sched_barrier(0);
        __builtin_amdgcn_s_barrier();
    }
#undef STGP64

#pragma unroll
    for (int i = 0; i < 2; ++i) {
#pragma unroll
        for (int j = 0; j < 4; ++j) {
            int colg = n0 + wn + j * 16 + l16;
#pragma unroll
            for (int rg = 0; rg < 4; ++rg) {
                int rowg = m0 + wm + i * 16 + quad * 4 + rg;
                size_t offo = (size_t)rowg * N + colg;
                float v = acc[i][j][rg];
                if (EPI == 0) {
                    outB[offo] = f2bf(v);
                } else if (EPI == 1) {
                    outF[offo] = res[offo] + v + bias[colg];
                } else if (EPI == 2) {
                    outB[offo] = f2bf(gelu_exact(v + bias[colg]));
                } else {
                    outF[offo] = v;
                }
            }
        }
    }
}

// ---------------- lm_head GEMM: 256x256 tile, 8 waves, ring-4 pipelined ----------------
// Round-8 schedule (ran + profiled: 170us, MfmaUtil 24%). Single change vs
// round 8: plain stores instead of nontemporal (NT inflated WRITE_SIZE
// 317MB vs 262MB ideal). The R9 lgkm-removal variant killed the container
// twice -> reverted; the drain stays.
__global__ __launch_bounds__(512, 2) void gemm_lmhead(
    const __hip_bfloat16* __restrict__ A, const __hip_bfloat16* __restrict__ Bt,
    float* __restrict__ out)
{
    constexpr int K = D_;        // 768
    constexpr int N = V_;        // 32000
    constexpr int NT = K / 32;   // 24 K-tiles
    __shared__ __hip_bfloat16 lds[4 * 16384];   // 4 ring buffers x 32 KB = 128 KiB

    const int tid  = threadIdx.x;
    const int wave = tid >> 6, lane = tid & 63;
    const int quad = lane >> 4, l16 = lane & 15;

    const int flat = blockIdx.x;                 // 0..999
    const int g = (flat & 7) * 125 + (flat >> 3);
    const int m0 = (g & 7) * 256, n0 = (g >> 3) * 256;

    const int wm = (wave >> 2) * 128;            // 2 waves in M
    const int wn = (wave & 3) * 64;              // 4 waves in N

    const int srow = tid >> 2;
    const int sq   = (tid & 3) ^ ((srow >> 1) & 3);
    const __hip_bfloat16* gA = A  + (size_t)(m0 + srow) * K + sq * 8;
    const __hip_bfloat16* gB = Bt + (size_t)(n0 + srow) * K + sq * 8;
    char* ldsc = (char*)lds;
    const int wb = wave * 1024;

#define STGP(tt) do {                                                        \
        const size_t ko = (size_t)(tt) * 32;                                 \
        char* bb = ldsc + ((tt) & 3) * 32768 + wb;                           \
        gl_lds16(gA + ko,                   (__hip_bfloat16*)(bb));          \
        gl_lds16(gA + (size_t)128 * K + ko, (__hip_bfloat16*)(bb + 8192));   \
        gl_lds16(gB + ko,                   (__hip_bfloat16*)(bb + 16384));  \
        gl_lds16(gB + (size_t)128 * K + ko, (__hip_bfloat16*)(bb + 24576));  \
    } while (0)

    const int xe = (quad ^ ((l16 >> 1) & 3)) * 16;

    float4_t acc[8][4];
#pragma unroll
    for (int i = 0; i < 8; ++i)
#pragma unroll
        for (int j = 0; j < 4; ++j) acc[i][j] = (float4_t){0.f, 0.f, 0.f, 0.f};

    STGP(0); STGP(1); STGP(2);
    asm volatile("s_waitcnt vmcnt(8)" ::: "memory");
    __builtin_amdgcn_sched_barrier(0);
    __builtin_amdgcn_s_barrier();

    for (int t = 0; t < NT; ++t) {
        if (t + 3 < NT) STGP(t + 3);
        const char* base = ldsc + (t & 3) * 32768;
        short8_t af[8], bfv[4];
#pragma unroll
        for (int i = 0; i < 8; ++i)
            af[i]  = *(const short8_t*)(base + (wm + i * 16 + l16) * 64 + xe);
#pragma unroll
        for (int j = 0; j < 4; ++j)
            bfv[j] = *(const short8_t*)(base + 16384 + (wn + j * 16 + l16) * 64 + xe);
        asm volatile("s_waitcnt lgkmcnt(0)" ::: "memory");
        __builtin_amdgcn_sched_barrier(0);
        __builtin_amdgcn_s_setprio(1);
#pragma unroll
        for (int i = 0; i < 8; ++i)
#pragma unroll
            for (int j = 0; j < 4; ++j)
                acc[i][j] = __builtin_amdgcn_mfma_f32_16x16x32_bf16(
                    af[i], bfv[j], acc[i][j], 0, 0, 0);
        __builtin_amdgcn_s_setprio(0);
        if (t + 3 < NT) {
            asm volatile("s_waitcnt vmcnt(8)" ::: "memory");
        } else if (t + 2 < NT) {
            asm volatile("s_waitcnt vmcnt(4)" ::: "memory");
        } else if (t + 1 < NT) {
            asm volatile("s_waitcnt vmcnt(0)" ::: "memory");
        }
        __builtin_amdgcn_sched_barrier(0);
        __builtin_amdgcn_s_barrier();
    }
#undef STGP

    // plain f32 stores (NT-store experiment reverted: +55MB WRITE_SIZE)
    float* orow = out + (size_t)(m0 + wm + quad * 4) * N + (n0 + wn + l16);
#pragma unroll
    for (int i = 0; i < 8; ++i)
#pragma unroll
        for (int j = 0; j < 4; ++j)
#pragma unroll
            for (int rg = 0; rg < 4; ++rg)
                orow[(size_t)(i * 16 + rg) * N + j * 16] = acc[i][j][rg];
}

// ---------------- launch ----------------
extern "C" void kernel_launch(void* const* d_in, const int* in_sizes, int n_in,
                              void* d_out, int out_size, void* d_ws, size_t ws_size,
                              hipStream_t stream)
{
    const int*   idx   = (const int*)d_in[0];
    const float* wte   = (const float*)d_in[1];
    const float* wpe   = (const float*)d_in[2];
    const float* ln1_a = (const float*)d_in[3];
    const float* ln1_w = (const float*)d_in[4];
    const float* ln1_b = (const float*)d_in[5];
    const float* wq    = (const float*)d_in[6];
    const float* wk    = (const float*)d_in[7];
    const float* wv    = (const float*)d_in[8];
    const float* wo    = (const float*)d_in[9];
    const float* bo    = (const float*)d_in[10];
    const float* ln2_a = (const float*)d_in[11];
    const float* ln2_w = (const float*)d_in[12];
    const float* ln2_b = (const float*)d_in[13];
    const float* w_fc  = (const float*)d_in[14];
    const float* b_fc  = (const float*)d_in[15];
    const float* w_pr  = (const float*)d_in[16];
    const float* b_pr  = (const float*)d_in[17];
    const float* lnf_a = (const float*)d_in[18];
    const float* lnf_w = (const float*)d_in[19];
    const float* lnf_b = (const float*)d_in[20];
    float* out = (float*)d_out;

    char* ws = (char*)d_ws;
    size_t off = 0;
    auto alloc = [&](size_t bytes) -> char* {
        char* p = ws + off;
        off += (bytes + 255) & ~(size_t)255;
        return p;
    };
    __hip_bfloat16* wqkv_t = (__hip_bfloat16*)alloc((size_t)L_ * QKVN_ * D_ * 2);
    __hip_bfloat16* wo_t   = (__hip_bfloat16*)alloc((size_t)L_ * D_ * D_ * 2);
    __hip_bfloat16* wfc_t  = (__hip_bfloat16*)alloc((size_t)L_ * FF_ * D_ * 2);
    __hip_bfloat16* wpr_t  = (__hip_bfloat16*)alloc((size_t)L_ * D_ * FF_ * 2);
    __hip_bfloat16* wte_b  = (__hip_bfloat16*)alloc((size_t)V_ * D_ * 2);
    float*          x      = (float*)alloc((size_t)M_ * D_ * 4);
    __hip_bfloat16* h      = (__hip_bfloat16*)alloc((size_t)M_ * D_ * 2);
    __hip_bfloat16* qkv    = (__hip_bfloat16*)alloc((size_t)M_ * QKVN_ * 2);
    __hip_bfloat16* attno  = (__hip_bfloat16*)alloc((size_t)M_ * D_ * 2);
    __hip_bfloat16* mid    = (__hip_bfloat16*)alloc((size_t)M_ * FF_ * 2);
    (void)ws_size; (void)in_sizes; (void)n_in; (void)out_size;

    // ---- weight prep: ONE dispatch (wte convert + all tconv sections) ----
    prep_kernel<<<dim3(24000 + 3 * 9216), 256, 0, stream>>>(
        wte, wte_b, wq, wk, wv, wo, wqkv_t, wo_t, w_fc, wfc_t, w_pr, wpr_t);

    // ---- embedding fused with layer-0 ln1 DyT ----
    dyt_kernel<true><<<dim3(M_), 256, 0, stream>>>(
        nullptr, x, h, ln1_w, ln1_b, ln1_a, idx, wte, wpe);

    // ---- transformer layers ----
    for (int l = 0; l < L_; ++l) {
        if (l > 0)
            dyt_kernel<false><<<dim3(M_), 256, 0, stream>>>(
                x, nullptr, h, ln1_w + l * D_, ln1_b + l * D_, ln1_a + l,
                nullptr, nullptr, nullptr);
        gemm_btp<0><<<dim3(QKVN_ / 128, M_ / 128), 256, 0, stream>>>(
            h, wqkv_t + (size_t)l * QKVN_ * D_, nullptr, qkv, nullptr, nullptr, M_, QKVN_, D_);
        fattn_kernel<<<dim3(T_ / 64, H_, B_), 256, 0, stream>>>(qkv, attno);
        gemm_btp64<1><<<dim3(D_ / 128, M_ / 64), 256, 0, stream>>>(
            attno, wo_t + (size_t)l * D_ * D_, x, nullptr, bo + l * D_, x, M_, D_, D_);
        dyt_kernel<false><<<dim3(M_), 256, 0, stream>>>(
            x, nullptr, h, ln2_w + l * D_, ln2_b + l * D_, ln2_a + l,
            nullptr, nullptr, nullptr);
        gemm_btp<2><<<dim3(FF_ / 128, M_ / 128), 256, 0, stream>>>(
            h, wfc_t + (size_t)l * FF_ * D_, nullptr, mid, b_fc + l * FF_, nullptr, M_, FF_, D_);
        gemm_btp64<1><<<dim3(D_ / 128, M_ / 64), 256, 0, stream>>>(
            mid, wpr_t + (size_t)l * D_ * FF_, x, nullptr, b_pr + l * D_, x, M_, D_, FF_);
    }

    // ---- final DyT + lm_head (256x256 ring-4, round-8 schedule, plain stores) ----
    dyt_kernel<false><<<dim3(M_), 256, 0, stream>>>(
        x, nullptr, h, lnf_w, lnf_b, lnf_a, nullptr, nullptr, nullptr);
    gemm_lmhead<<<dim3((M_ / 256) * (V_ / 256)), 512, 0, stream>>>(h, wte_b, out);
}